// Round 11
// baseline (876.357 us; speedup 1.0000x reference)
//
#include <hip/hip_runtime.h>

#define NN 50000
#define NE 400000
#define FIN 64
#define EIN 16
#define H 128
#define NL 4
#define NG 256
#define NOUT 12
#define EPSV 1e-5f

#define SB 256
#define NBLK ((NN + SB - 1) / SB)    // 196
#define GB2 ((NN + 127) / 128)       // 391 (128-row MFMA tiles)
#define GB3 ((NN + 63) / 64)         // 782 (64-row tiles for k_pgemm)
#define NP64 (NN * 64)               // dwords per [NN,H] bf16 plane

typedef short bf16x8 __attribute__((ext_vector_type(8)));
typedef float f32x4 __attribute__((ext_vector_type(4)));
typedef float v2f __attribute__((ext_vector_type(2)));

__device__ __forceinline__ unsigned short f2bf(float f) {
    unsigned u = __float_as_uint(f);
    u += 0x7fffu + ((u >> 16) & 1u);
    return (unsigned short)(u >> 16);
}

__device__ __forceinline__ float bflo(unsigned u) { return __uint_as_float(u << 16); }
__device__ __forceinline__ float bfhi(unsigned u) { return __uint_as_float(u & 0xffff0000u); }

// ---------------- setup kernels ----------------
__global__ void k_hist(const int* __restrict__ dst, int* __restrict__ deg) {
    int e = blockIdx.x * 256 + threadIdx.x;
    if (e < NE) atomicAdd(&deg[dst[e]], 1);
}

__global__ void k_scan1(const int* __restrict__ deg, int* __restrict__ partial) {
    __shared__ int sm[256];
    int i = blockIdx.x * 256 + threadIdx.x;
    sm[threadIdx.x] = (i < NN) ? deg[i] : 0;
    __syncthreads();
    for (int s = 128; s > 0; s >>= 1) {
        if (threadIdx.x < s) sm[threadIdx.x] += sm[threadIdx.x + s];
        __syncthreads();
    }
    if (threadIdx.x == 0) partial[blockIdx.x] = sm[0];
}

__global__ void k_scan2(int* __restrict__ partial, int* __restrict__ row_ptr, int nblk) {
    __shared__ int sm[256];
    int t = threadIdx.x;
    sm[t] = (t < nblk) ? partial[t] : 0;
    __syncthreads();
    for (int off = 1; off < 256; off <<= 1) {
        int v = (t >= off) ? sm[t - off] : 0;
        __syncthreads();
        sm[t] += v;
        __syncthreads();
    }
    int excl = (t == 0) ? 0 : sm[t - 1];
    if (t < nblk) partial[t] = excl;
    if (t == 0) row_ptr[0] = 0;
}

__global__ void k_scan3(const int* __restrict__ deg, const int* __restrict__ partial,
                        int* __restrict__ row_ptr) {
    __shared__ int sm[256];
    int t = threadIdx.x;
    int i = blockIdx.x * 256 + t;
    sm[t] = (i < NN) ? deg[i] : 0;
    __syncthreads();
    for (int off = 1; off < 256; off <<= 1) {
        int v = (t >= off) ? sm[t - off] : 0;
        __syncthreads();
        sm[t] += v;
        __syncthreads();
    }
    if (i < NN) row_ptr[i + 1] = partial[blockIdx.x] + sm[t];
}

__global__ void k_fill(const int* __restrict__ src, const int* __restrict__ dst,
                       const int* __restrict__ row_ptr, int* __restrict__ cursor,
                       int* __restrict__ csr_src, int* __restrict__ csr_eid) {
    int e = blockIdx.x * 256 + threadIdx.x;
    if (e >= NE) return;
    int d = dst[e];
    int pos = atomicAdd(&cursor[d], 1);
    int slot = row_ptr[d] + pos;
    csr_src[slot] = src[e];
    csr_eid[slot] = e;
}

// eattr permuted into CSR slot order, fp32 (one-time; uniform rows -> s_loads in k_agg2)
__global__ void k_eperm(const float* __restrict__ eattr, const int* __restrict__ csr_eid,
                        float* __restrict__ eattrF) {
    int idx = blockIdx.x * 256 + threadIdx.x;
    if (idx >= NE * EIN) return;
    int slot = idx >> 4, j = idx & 15;
    eattrF[idx] = eattr[(size_t)csr_eid[slot] * EIN + j];
}

__global__ void k_sumlog(const int* __restrict__ deg, float* __restrict__ sum) {
    int i = blockIdx.x * 256 + threadIdx.x;
    float v = (i < NN) ? log1pf((float)deg[i]) : 0.f;
    #pragma unroll
    for (int off = 32; off > 0; off >>= 1) v += __shfl_down(v, off, 64);
    if ((threadIdx.x & 63) == 0) atomicAdd(sum, v);
}

__global__ void k_scalers(const int* __restrict__ deg, const float* __restrict__ sumlog,
                          float* __restrict__ amp, float* __restrict__ att) {
    int i = blockIdx.x * 256 + threadIdx.x;
    if (i >= NN) return;
    float avg = sumlog[0] / (float)NN;
    float degc = fmaxf((float)deg[i], 1.0f);
    float la = logf(degc + 1.0f);
    amp[i] = la / avg;
    att[i] = avg / la;
}

// ---------------- M_l = encW_l @ preW2_l  (128x128 fp32, tiled) ----------------
__global__ __launch_bounds__(256) void k_encfold(const float* __restrict__ encW,
                                                 const float* __restrict__ preW,
                                                 float* __restrict__ M) {
    __shared__ float As[32][68];
    __shared__ float Bs[32][128];
    int l = blockIdx.y;
    const float* A = encW + (size_t)l * H * H;
    const float* Bp = preW + (size_t)l * 3 * H * H + 2 * H * H;
    float* Ml = M + (size_t)l * H * H;
    int m0 = blockIdx.x * 64;
    int tid = threadIdx.x;
    int tx = tid & 31, ty = tid >> 5;
    float4 acc[8];
    #pragma unroll
    for (int r = 0; r < 8; r++) acc[r] = make_float4(0, 0, 0, 0);
    int f = tid & 7, r0 = tid >> 3;
    int cf = tid & 31, kr0 = tid >> 5;
    for (int k0 = 0; k0 < H; k0 += 32) {
        #pragma unroll
        for (int hh = 0; hh < 2; hh++) {
            int r = r0 + hh * 32;
            float4 v = *(const float4*)(A + (size_t)(m0 + r) * H + k0 + f * 4);
            As[f * 4 + 0][r] = v.x; As[f * 4 + 1][r] = v.y;
            As[f * 4 + 2][r] = v.z; As[f * 4 + 3][r] = v.w;
        }
        #pragma unroll
        for (int hh = 0; hh < 4; hh++) {
            int kr = kr0 + hh * 8;
            *(float4*)&Bs[kr][cf * 4] = *(const float4*)(Bp + (size_t)(k0 + kr) * H + cf * 4);
        }
        __syncthreads();
        #pragma unroll
        for (int kk = 0; kk < 32; kk++) {
            float4 b = *(float4*)&Bs[kk][tx * 4];
            float4 a0 = *(float4*)&As[kk][ty * 8];
            float4 a1 = *(float4*)&As[kk][ty * 8 + 4];
            acc[0].x = fmaf(a0.x, b.x, acc[0].x); acc[0].y = fmaf(a0.x, b.y, acc[0].y);
            acc[0].z = fmaf(a0.x, b.z, acc[0].z); acc[0].w = fmaf(a0.x, b.w, acc[0].w);
            acc[1].x = fmaf(a0.y, b.x, acc[1].x); acc[1].y = fmaf(a0.y, b.y, acc[1].y);
            acc[1].z = fmaf(a0.y, b.z, acc[1].z); acc[1].w = fmaf(a0.y, b.w, acc[1].w);
            acc[2].x = fmaf(a0.z, b.x, acc[2].x); acc[2].y = fmaf(a0.z, b.y, acc[2].y);
            acc[2].z = fmaf(a0.z, b.z, acc[2].z); acc[2].w = fmaf(a0.z, b.w, acc[2].w);
            acc[3].x = fmaf(a0.w, b.x, acc[3].x); acc[3].y = fmaf(a0.w, b.y, acc[3].y);
            acc[3].z = fmaf(a0.w, b.z, acc[3].z); acc[3].w = fmaf(a0.w, b.w, acc[3].w);
            acc[4].x = fmaf(a1.x, b.x, acc[4].x); acc[4].y = fmaf(a1.x, b.y, acc[4].y);
            acc[4].z = fmaf(a1.x, b.z, acc[4].z); acc[4].w = fmaf(a1.x, b.w, acc[4].w);
            acc[5].x = fmaf(a1.y, b.x, acc[5].x); acc[5].y = fmaf(a1.y, b.y, acc[5].y);
            acc[5].z = fmaf(a1.y, b.z, acc[5].z); acc[5].w = fmaf(a1.y, b.w, acc[5].w);
            acc[6].x = fmaf(a1.z, b.x, acc[6].x); acc[6].y = fmaf(a1.z, b.y, acc[6].y);
            acc[6].z = fmaf(a1.z, b.z, acc[6].z); acc[6].w = fmaf(a1.z, b.w, acc[6].w);
            acc[7].x = fmaf(a1.w, b.x, acc[7].x); acc[7].y = fmaf(a1.w, b.y, acc[7].y);
            acc[7].z = fmaf(a1.w, b.z, acc[7].z); acc[7].w = fmaf(a1.w, b.w, acc[7].w);
        }
        __syncthreads();
    }
    #pragma unroll
    for (int rr = 0; rr < 8; rr++) {
        int row = m0 + ty * 8 + rr;
        *(float4*)(Ml + (size_t)row * H + tx * 4) = acc[rr];
    }
}

// Kc_l = embW @ M_l  (16x128 per layer)
__global__ void k_kprep(const float* __restrict__ embW, const float* __restrict__ M,
                        float* __restrict__ Kc) {
    int l = blockIdx.y;
    int idx = blockIdx.x * 256 + threadIdx.x;   // 2048 elems
    int r = idx >> 7, j = idx & 127;
    const float* Ml = M + (size_t)l * H * H;
    float s = 0.f;
    for (int k = 0; k < H; k++) s = fmaf(embW[r * H + k], Ml[k * H + j], s);
    Kc[l * 16 * H + idx] = s;
}

// cc_l = (emb_b @ encW_l + enc_b_l) @ preW2_l + pre_b_l
__global__ void k_cprep(const float* __restrict__ emb_b, const float* __restrict__ encW,
                        const float* __restrict__ enc_b, const float* __restrict__ preW,
                        const float* __restrict__ pre_b, float* __restrict__ cc) {
    __shared__ float b1[H];
    int l = blockIdx.x, t = threadIdx.x;
    const float* encWl = encW + (size_t)l * H * H;
    const float* preW2 = preW + (size_t)l * 3 * H * H + 2 * H * H;
    float s = enc_b[l * H + t];
    for (int k = 0; k < H; k++) s = fmaf(emb_b[k], encWl[k * H + t], s);
    b1[t] = s;
    __syncthreads();
    float c = pre_b[l * H + t];
    for (int k = 0; k < H; k++) c = fmaf(b1[k], preW2[k * H + t], c);
    cc[l * H + t] = c;
}

// ---------------- weight transpose+cast: D[n][k] = bf16(S[k][n]), S has 128 cols ----------------
struct TD { const float* S; unsigned short* D; int K; };
struct TDs { TD t[9]; };

__global__ void k_prepw(TDs p) {
    TD d = p.t[blockIdx.y];
    int idx = blockIdx.x * 256 + threadIdx.x;
    int total = d.K << 7;
    if (idx < total) {
        int k = idx >> 7, n = idx & 127;
        d.D[(size_t)n * d.K + k] = f2bf(d.S[(size_t)k * 128 + n]);
    }
}

__global__ void k_cast(const float* __restrict__ S, unsigned short* __restrict__ D, int n) {
    int i = blockIdx.x * 256 + threadIdx.x;
    if (i < n) D[i] = f2bf(S[i]);
}

// ---------------- weight fold: fold_l = postW_l @ linW_l  (fp32 acc, bf16-T out) --------------
__global__ __launch_bounds__(256) void k_wfold(const float* __restrict__ postW,
                                               const float* __restrict__ linW,
                                               unsigned short* __restrict__ Wt3,
                                               unsigned short* __restrict__ foldT) {
    __shared__ float As[32][68];
    __shared__ float Bs[32][128];
    int l = blockIdx.y;
    const float* A = postW + (size_t)l * 13 * H * H;   // [1664][128]
    const float* Bp = linW + (size_t)l * H * H;        // [128][128]
    int m0 = blockIdx.x * 64;
    int tid = threadIdx.x;
    int tx = tid & 31, ty = tid >> 5;
    float4 acc[8];
    #pragma unroll
    for (int r = 0; r < 8; r++) acc[r] = make_float4(0, 0, 0, 0);
    int f = tid & 7, r0 = tid >> 3;
    int cf = tid & 31, kr0 = tid >> 5;
    for (int k0 = 0; k0 < H; k0 += 32) {
        #pragma unroll
        for (int hh = 0; hh < 2; hh++) {
            int r = r0 + hh * 32;
            float4 v = *(const float4*)(A + (size_t)(m0 + r) * H + k0 + f * 4);
            As[f * 4 + 0][r] = v.x; As[f * 4 + 1][r] = v.y;
            As[f * 4 + 2][r] = v.z; As[f * 4 + 3][r] = v.w;
        }
        #pragma unroll
        for (int hh = 0; hh < 4; hh++) {
            int kr = kr0 + hh * 8;
            *(float4*)&Bs[kr][cf * 4] = *(const float4*)(Bp + (size_t)(k0 + kr) * H + cf * 4);
        }
        __syncthreads();
        #pragma unroll
        for (int kk = 0; kk < 32; kk++) {
            float4 b = *(float4*)&Bs[kk][tx * 4];
            float4 a0 = *(float4*)&As[kk][ty * 8];
            float4 a1 = *(float4*)&As[kk][ty * 8 + 4];
            acc[0].x = fmaf(a0.x, b.x, acc[0].x); acc[0].y = fmaf(a0.x, b.y, acc[0].y);
            acc[0].z = fmaf(a0.x, b.z, acc[0].z); acc[0].w = fmaf(a0.x, b.w, acc[0].w);
            acc[1].x = fmaf(a0.y, b.x, acc[1].x); acc[1].y = fmaf(a0.y, b.y, acc[1].y);
            acc[1].z = fmaf(a0.y, b.z, acc[1].z); acc[1].w = fmaf(a0.y, b.w, acc[1].w);
            acc[2].x = fmaf(a0.z, b.x, acc[2].x); acc[2].y = fmaf(a0.z, b.y, acc[2].y);
            acc[2].z = fmaf(a0.z, b.z, acc[2].z); acc[2].w = fmaf(a0.z, b.w, acc[2].w);
            acc[3].x = fmaf(a0.w, b.x, acc[3].x); acc[3].y = fmaf(a0.w, b.y, acc[3].y);
            acc[3].z = fmaf(a0.w, b.z, acc[3].z); acc[3].w = fmaf(a0.w, b.w, acc[3].w);
            acc[4].x = fmaf(a1.x, b.x, acc[4].x); acc[4].y = fmaf(a1.x, b.y, acc[4].y);
            acc[4].z = fmaf(a1.x, b.z, acc[4].z); acc[4].w = fmaf(a1.x, b.w, acc[4].w);
            acc[5].x = fmaf(a1.y, b.x, acc[5].x); acc[5].y = fmaf(a1.y, b.y, acc[5].y);
            acc[5].z = fmaf(a1.y, b.z, acc[5].z); acc[5].w = fmaf(a1.y, b.w, acc[5].w);
            acc[6].x = fmaf(a1.z, b.x, acc[6].x); acc[6].y = fmaf(a1.z, b.y, acc[6].y);
            acc[6].z = fmaf(a1.z, b.z, acc[6].z); acc[6].w = fmaf(a1.z, b.w, acc[6].w);
            acc[7].x = fmaf(a1.w, b.x, acc[7].x); acc[7].y = fmaf(a1.w, b.y, acc[7].y);
            acc[7].z = fmaf(a1.w, b.z, acc[7].z); acc[7].w = fmaf(a1.w, b.w, acc[7].w);
        }
        __syncthreads();
    }
    unsigned short* w2 = Wt3 + (size_t)(l * 3 + 2) * H * H;
    unsigned short* ft = foldT + (size_t)l * 128 * 1664;
    int r = m0 + ty * 8;
    #pragma unroll
    for (int c = 0; c < 4; c++) {
        int n = tx * 4 + c;
        unsigned short tmp[8] __attribute__((aligned(16)));
        #pragma unroll
        for (int rr = 0; rr < 8; rr++) tmp[rr] = f2bf(((const float*)&acc[rr])[c]);
        unsigned short* dstp = (r < 128) ? (w2 + (size_t)n * 128 + r)
                                         : (ft + (size_t)n * 1664 + r);
        *(uint4*)dstp = *(const uint4*)tmp;
    }
}

// bias' = pb @ linW + lb  (per layer)
__global__ void k_bfold(const float* __restrict__ pb, const float* __restrict__ lb,
                        const float* __restrict__ linW, float* __restrict__ cf) {
    int l = blockIdx.x, n = threadIdx.x;
    const float* B = linW + (size_t)l * H * H;
    float s = lb[l * H + n];
    for (int j = 0; j < H; j++) s = fmaf(pb[l * H + j], B[j * H + n], s);
    cf[l * H + n] = s;
}

// ---------------- bf16 MFMA GEMM (swapped-operand D^T epilogue, LDS-staged C) ----------------
__global__ __launch_bounds__(256, 4) void k_mgemm(
    const unsigned short* __restrict__ A, int lda, int K, int nch,
    const unsigned short* __restrict__ Bt, int ldb, int bstride_y,
    const float* __restrict__ bias, unsigned short* __restrict__ outB)
{
    __shared__ unsigned short SH[2][128][72];   // staging; reused as 128x136 C-tile
    const unsigned short* Btp = Bt + (size_t)blockIdx.x * bstride_y;
    int m0 = blockIdx.y * 128;
    int tid = threadIdx.x;
    int wave = tid >> 6, lane = tid & 63;
    int wr = wave >> 1, wc = wave & 1;
    int ln = lane & 15, q = lane >> 4;

    f32x4 acc[4][4];
    #pragma unroll
    for (int a = 0; a < 4; a++)
        #pragma unroll
        for (int b = 0; b < 4; b++) acc[a][b] = (f32x4){0.f, 0.f, 0.f, 0.f};

    for (int c = 0; c < nch; c++) {
        int col = c * 64;
        #pragma unroll
        for (int i0 = 0; i0 < 4; i0++) {
            int i = tid + i0 * 256;
            int row = i >> 3, seg = i & 7;
            uint4 bv = *(const uint4*)(Btp + (size_t)row * ldb + col + seg * 8);
            *(uint4*)(&SH[1][row][seg * 8]) = bv;
            int rowg = m0 + row;
            uint4 av = make_uint4(0, 0, 0, 0);
            if (rowg < NN) av = *(const uint4*)(A + (size_t)rowg * lda + col + seg * 8);
            *(uint4*)(&SH[0][row][seg * 8]) = av;
        }
        __syncthreads();
        #pragma unroll
        for (int kq = 0; kq < 2; kq++) {
            bf16x8 af[4], bfr[4];
            #pragma unroll
            for (int f = 0; f < 4; f++) {
                af[f]  = *(const bf16x8*)(&SH[0][wr * 64 + f * 16 + ln][kq * 32 + q * 8]);
                bfr[f] = *(const bf16x8*)(&SH[1][wc * 64 + f * 16 + ln][kq * 32 + q * 8]);
            }
            #pragma unroll
            for (int fr = 0; fr < 4; fr++)
                #pragma unroll
                for (int fc = 0; fc < 4; fc++)
                    acc[fr][fc] = __builtin_amdgcn_mfma_f32_16x16x32_bf16(
                        bfr[fc], af[fr], acc[fr][fc], 0, 0, 0);   // swapped: D^T
        }
        __syncthreads();
    }

    unsigned short* CT = &SH[0][0][0];   // 128 x (stride 136)
    #pragma unroll
    for (int fr = 0; fr < 4; fr++) {
        int rloc = wr * 64 + fr * 16 + ln;
        #pragma unroll
        for (int fc = 0; fc < 4; fc++) {
            int colb = wc * 64 + fc * 16 + q * 4;
            float4 bv = bias ? *(const float4*)(bias + colb) : make_float4(0, 0, 0, 0);
            unsigned short tmp[4] __attribute__((aligned(8)));
            tmp[0] = f2bf(acc[fr][fc][0] + bv.x);
            tmp[1] = f2bf(acc[fr][fc][1] + bv.y);
            tmp[2] = f2bf(acc[fr][fc][2] + bv.z);
            tmp[3] = f2bf(acc[fr][fc][3] + bv.w);
            *(uint2*)(&CT[rloc * 136 + colb]) = *(const uint2*)tmp;
        }
    }
    __syncthreads();
    unsigned short* outBp = outB + (size_t)blockIdx.x * NN * H;
    #pragma unroll
    for (int i0 = 0; i0 < 8; i0++) {
        int idx = tid + i0 * 256;
        int row = idx >> 4, seg = idx & 15;
        int rowg = m0 + row;
        if (rowg < NN)
            *(uint4*)(outBp + (size_t)rowg * H + seg * 8) = *(const uint4*)(&CT[row * 136 + seg * 8]);
    }
}

// ---------------- fused parts GEMM + combine ----------------
// h = relu(hA' + p0 + amp*p1 + att*p2 + bias') where p_g = agg @ (B_g@linW).
// Block: 64 rows x 128 cols, g-loop over 3 scale groups (K=512 each), in-register fold.
__global__ __launch_bounds__(256, 3) void k_pgemm(
    const unsigned short* __restrict__ A,      // aggb [NN][512]
    const unsigned short* __restrict__ Bt,     // foldT_l: [n][1664], k in [128,1664)
    const unsigned short* __restrict__ ha,     // planesB plane2 [NN][128]
    const float* __restrict__ amp, const float* __restrict__ att,
    const float* __restrict__ biasf,           // cfold_l [128]
    unsigned short* __restrict__ outB, float* __restrict__ outF)
{
    __shared__ unsigned short SH[64 * 72 + 128 * 72];
    unsigned short (*As)[72] = (unsigned short(*)[72])SH;
    unsigned short (*Bs)[72] = (unsigned short(*)[72])(SH + 64 * 72);
    int m0 = blockIdx.x * 64;
    int tid = threadIdx.x;
    int wave = tid >> 6, lane = tid & 63;
    int wr = wave >> 1, wc = wave & 1;
    int ln = lane & 15, q = lane >> 4;

    float sc1[2], sc2[2];
    #pragma unroll
    for (int fr = 0; fr < 2; fr++) {
        int row = m0 + wr * 32 + fr * 16 + ln;
        row = row < NN ? row : NN - 1;
        sc1[fr] = amp[row];
        sc2[fr] = att[row];
    }

    f32x4 tot[2][4];
    #pragma unroll
    for (int a = 0; a < 2; a++)
        #pragma unroll
        for (int b = 0; b < 4; b++) tot[a][b] = (f32x4){0.f, 0.f, 0.f, 0.f};

    for (int g = 0; g < 3; g++) {
        f32x4 acc[2][4];
        #pragma unroll
        for (int a = 0; a < 2; a++)
            #pragma unroll
            for (int b = 0; b < 4; b++) acc[a][b] = (f32x4){0.f, 0.f, 0.f, 0.f};

        for (int c = 0; c < 8; c++) {
            int kofs = 128 + g * 512 + c * 64;
            #pragma unroll
            for (int i0 = 0; i0 < 2; i0++) {
                int i = tid + i0 * 256;            // 0..511
                int row = i >> 3, seg = i & 7;     // 64 rows x 8 segs
                int rowg = m0 + row;
                uint4 av = make_uint4(0, 0, 0, 0);
                if (rowg < NN) av = *(const uint4*)(A + (size_t)rowg * 512 + c * 64 + seg * 8);
                *(uint4*)(&As[row][seg * 8]) = av;
            }
            #pragma unroll
            for (int i0 = 0; i0 < 4; i0++) {
                int i = tid + i0 * 256;            // 0..1023
                int n = i >> 3, seg = i & 7;       // 128 n-rows x 8 segs
                uint4 bv = *(const uint4*)(Bt + (size_t)n * 1664 + kofs + seg * 8);
                *(uint4*)(&Bs[n][seg * 8]) = bv;
            }
            __syncthreads();
            #pragma unroll
            for (int kq = 0; kq < 2; kq++) {
                bf16x8 af[2], bfr[4];
                #pragma unroll
                for (int f = 0; f < 2; f++)
                    af[f] = *(const bf16x8*)(&As[wr * 32 + f * 16 + ln][kq * 32 + q * 8]);
                #pragma unroll
                for (int f = 0; f < 4; f++)
                    bfr[f] = *(const bf16x8*)(&Bs[wc * 64 + f * 16 + ln][kq * 32 + q * 8]);
                #pragma unroll
                for (int fr = 0; fr < 2; fr++)
                    #pragma unroll
                    for (int fc = 0; fc < 4; fc++)
                        acc[fr][fc] = __builtin_amdgcn_mfma_f32_16x16x32_bf16(
                            bfr[fc], af[fr], acc[fr][fc], 0, 0, 0);   // swapped: D^T
            }
            __syncthreads();
        }
        #pragma unroll
        for (int fr = 0; fr < 2; fr++) {
            float s = (g == 0) ? 1.0f : (g == 1 ? sc1[fr] : sc2[fr]);
            #pragma unroll
            for (int fc = 0; fc < 4; fc++) {
                tot[fr][fc][0] = fmaf(s, acc[fr][fc][0], tot[fr][fc][0]);
                tot[fr][fc][1] = fmaf(s, acc[fr][fc][1], tot[fr][fc][1]);
                tot[fr][fc][2] = fmaf(s, acc[fr][fc][2], tot[fr][fc][2]);
                tot[fr][fc][3] = fmaf(s, acc[fr][fc][3], tot[fr][fc][3]);
            }
        }
    }

    // epilogue: + hA' + bias', relu; LDS-staged coalesced bf16 store (+fp32 for last layer)
    unsigned short* CT = SH;   // 64 x (stride 136)
    #pragma unroll
    for (int fr = 0; fr < 2; fr++) {
        int rloc = wr * 32 + fr * 16 + ln;
        int row = m0 + rloc;
        int rc = row < NN ? row : NN - 1;
        #pragma unroll
        for (int fc = 0; fc < 4; fc++) {
            int colb = wc * 64 + fc * 16 + q * 4;
            float4 bv = *(const float4*)(biasf + colb);
            uint2 h2 = *(const uint2*)(ha + (size_t)rc * H + colb);
            float v0 = fmaxf(tot[fr][fc][0] + bflo(h2.x) + bv.x, 0.f);
            float v1 = fmaxf(tot[fr][fc][1] + bfhi(h2.x) + bv.y, 0.f);
            float v2 = fmaxf(tot[fr][fc][2] + bflo(h2.y) + bv.z, 0.f);
            float v3 = fmaxf(tot[fr][fc][3] + bfhi(h2.y) + bv.w, 0.f);
            unsigned short tmp[4] __attribute__((aligned(8)));
            tmp[0] = f2bf(v0); tmp[1] = f2bf(v1); tmp[2] = f2bf(v2); tmp[3] = f2bf(v3);
            *(uint2*)(&CT[rloc * 136 + colb]) = *(const uint2*)tmp;
            if (outF && row < NN)
                *(float4*)(outF + (size_t)row * H + colb) = make_float4(v0, v1, v2, v3);
        }
    }
    __syncthreads();
    #pragma unroll
    for (int i0 = 0; i0 < 4; i0++) {
        int idx = tid + i0 * 256;              // 0..1023
        int row = idx >> 4, seg = idx & 15;    // 64 rows x 16 segs
        int rowg = m0 + row;
        if (rowg < NN)
            *(uint4*)(outB + (size_t)rowg * H + seg * 8) = *(const uint4*)(&CT[row * 136 + seg * 8]);
    }
}

// ---------------- fused aggregation: one wave per node ----------------
// eF register-pipelined one slot-pair ahead; hs gathers pipelined depth-4.
__global__ __launch_bounds__(256) void k_agg2(
    const unsigned short* __restrict__ pd, const unsigned short* __restrict__ ps,
    const float* __restrict__ eF,         // [E][16] fp32, slot-ordered
    const int* __restrict__ csr_src, const int* __restrict__ row_ptr,
    const float* __restrict__ Kl, const float* __restrict__ cl,
    unsigned short* __restrict__ agg)
{
    int wv = threadIdx.x >> 6, lane = threadIdx.x & 63;
    int i = blockIdx.x * 4 + wv;
    int d0 = lane * 2;
    v2f kr[16];
    #pragma unroll
    for (int k = 0; k < 16; k++) kr[k] = *(const v2f*)(Kl + k * H + d0);
    v2f c2 = *(const v2f*)(cl + d0);
    unsigned hd = *(const unsigned*)(pd + (size_t)i * H + d0);
    v2f base = c2 + (v2f){bflo(hd), bfhi(hd)};
    int rs = __builtin_amdgcn_readfirstlane(row_ptr[i]);
    int re = __builtin_amdgcn_readfirstlane(row_ptr[i + 1]);
    v2f s = (v2f){0.f, 0.f}, qv = (v2f){0.f, 0.f};
    v2f mn = (v2f){3.0e38f, 3.0e38f}, mx = (v2f){-3.0e38f, -3.0e38f};

    // pipelines: hs depth-4, eF one pair ahead
    unsigned hs0, hs1, hs2, hs3;
    float4 eA[4], eB[4];
    {
        int a0 = (rs < re)     ? __builtin_amdgcn_readfirstlane(csr_src[rs])     : 0;
        int a1 = (rs + 1 < re) ? __builtin_amdgcn_readfirstlane(csr_src[rs + 1]) : 0;
        int a2 = (rs + 2 < re) ? __builtin_amdgcn_readfirstlane(csr_src[rs + 2]) : 0;
        int a3 = (rs + 3 < re) ? __builtin_amdgcn_readfirstlane(csr_src[rs + 3]) : 0;
        hs0 = *(const unsigned*)(ps + (size_t)a0 * H + d0);
        hs1 = *(const unsigned*)(ps + (size_t)a1 * H + d0);
        hs2 = *(const unsigned*)(ps + (size_t)a2 * H + d0);
        hs3 = *(const unsigned*)(ps + (size_t)a3 * H + d0);
        int s0 = (rs < re) ? rs : 0;
        int s1 = (rs + 1 < re) ? rs + 1 : s0;
        const float4* p0 = (const float4*)(eF + (size_t)s0 * EIN);
        const float4* p1 = (const float4*)(eF + (size_t)s1 * EIN);
        #pragma unroll
        for (int w = 0; w < 4; w++) { eA[w] = p0[w]; eB[w] = p1[w]; }
    }

    int slot = rs;
    for (; slot + 1 < re; slot += 2) {
        int p0i = (slot + 4 < re) ? __builtin_amdgcn_readfirstlane(csr_src[slot + 4]) : 0;
        int p1i = (slot + 5 < re) ? __builtin_amdgcn_readfirstlane(csr_src[slot + 5]) : 0;
        unsigned hsN0 = *(const unsigned*)(ps + (size_t)p0i * H + d0);
        unsigned hsN1 = *(const unsigned*)(ps + (size_t)p1i * H + d0);
        // prefetch next eF pair (clamped addresses)
        int s2 = (slot + 2 < re) ? slot + 2 : slot;
        int s3 = (slot + 3 < re) ? slot + 3 : slot;
        const float4* pn0 = (const float4*)(eF + (size_t)s2 * EIN);
        const float4* pn1 = (const float4*)(eF + (size_t)s3 * EIN);
        float4 nA[4], nB[4];
        #pragma unroll
        for (int w = 0; w < 4; w++) { nA[w] = pn0[w]; nB[w] = pn1[w]; }

        const float* ea = (const float*)eA;
        const float* eb = (const float*)eB;
        v2f a = base + (v2f){bflo(hs0), bfhi(hs0)};
        v2f c = base + (v2f){bflo(hs1), bfhi(hs1)};
        #pragma unroll
        for (int j = 0; j < 16; j++) {
            float e1 = ea[j], e2 = eb[j];
            a = (v2f){e1, e1} * kr[j] + a;
            c = (v2f){e2, e2} * kr[j] + c;
        }
        s = s + a + c;
        qv = a * a + (c * c + qv);
        mn.x = fminf(mn.x, fminf(a.x, c.x)); mn.y = fminf(mn.y, fminf(a.y, c.y));
        mx.x = fmaxf(mx.x, fmaxf(a.x, c.x)); mx.y = fmaxf(mx.y, fmaxf(a.y, c.y));
        hs0 = hs2; hs1 = hs3; hs2 = hsN0; hs3 = hsN1;
        #pragma unroll
        for (int w = 0; w < 4; w++) { eA[w] = nA[w]; eB[w] = nB[w]; }
    }
    if (slot < re) {   // odd tail
        const float* ea = (const float*)eA;
        v2f a = base + (v2f){bflo(hs0), bfhi(hs0)};
        #pragma unroll
        for (int j = 0; j < 16; j++) {
            float e1 = ea[j];
            a = (v2f){e1, e1} * kr[j] + a;
        }
        s = s + a;
        qv = a * a + qv;
        mn.x = fminf(mn.x, a.x); mn.y = fminf(mn.y, a.y);
        mx.x = fmaxf(mx.x, a.x); mx.y = fmaxf(mx.y, a.y);
    }

    int dg = re - rs;
    float dinv = 1.0f / fmaxf((float)dg, 1.0f);
    v2f me = s * (v2f){dinv, dinv};
    float sdx = sqrtf(fmaxf(qv.x * dinv - me.x * me.x, 0.f) + EPSV);
    float sdy = sqrtf(fmaxf(qv.y * dinv - me.y * me.y, 0.f) + EPSV);
    if (dg == 0) { mn = (v2f){0.f, 0.f}; mx = (v2f){0.f, 0.f}; }
    unsigned short* ap = agg + (size_t)i * 512 + d0;
    *(unsigned*)(ap)       = (unsigned)f2bf(me.x) | ((unsigned)f2bf(me.y) << 16);
    *(unsigned*)(ap + 128) = (unsigned)f2bf(mn.x) | ((unsigned)f2bf(mn.y) << 16);
    *(unsigned*)(ap + 256) = (unsigned)f2bf(mx.x) | ((unsigned)f2bf(mx.y) << 16);
    *(unsigned*)(ap + 384) = (unsigned)f2bf(sdx)  | ((unsigned)f2bf(sdy)  << 16);
}

// ---------------- pooling + head ----------------
__device__ __forceinline__ int lbound(const int* a, int n, int v) {
    int lo = 0, hi = n;
    while (lo < hi) { int m = (lo + hi) >> 1; if (a[m] < v) lo = m + 1; else hi = m; }
    return lo;
}

__global__ __launch_bounds__(256) void k_pool(const float* __restrict__ h,
                                              const int* __restrict__ batch,
                                              const float* __restrict__ headW,
                                              const float* __restrict__ headb,
                                              float* __restrict__ out) {
    __shared__ float sm[256];
    int g = blockIdx.x;
    int t = threadIdx.x;
    int col = t & 127;
    int half = t >> 7;
    int lo = lbound(batch, NN, g);
    int hi = lbound(batch, NN, g + 1);
    int mid = lo + ((hi - lo) >> 1);
    int b0 = half ? mid : lo;
    int b1 = half ? hi : mid;
    float acc = 0.f;
    for (int i = b0; i < b1; i++) acc += h[(size_t)i * H + col];
    sm[t] = acc;
    __syncthreads();
    if (t < 128) sm[t] += sm[t + 128];
    __syncthreads();
    if (t < NOUT) {
        float r = headb[t];
        for (int j = 0; j < H; j++) r = fmaf(sm[j], headW[j * NOUT + t], r);
        out[g * NOUT + t] = r;
    }
}

// ---------------- launch ----------------
extern "C" void kernel_launch(void* const* d_in, const int* in_sizes, int n_in,
                              void* d_out, int out_size, void* d_ws, size_t ws_size,
                              hipStream_t stream) {
    const float* x          = (const float*)d_in[0];
    const float* edge_attr  = (const float*)d_in[1];
    const int*   src        = (const int*)d_in[2];
    const int*   dst        = (const int*)d_in[3];
    const int*   batch      = (const int*)d_in[4];
    const float* node_emb_W = (const float*)d_in[5];
    const float* node_emb_b = (const float*)d_in[6];
    const float* edge_emb_W = (const float*)d_in[7];
    const float* edge_emb_b = (const float*)d_in[8];
    const float* edge_enc_W = (const float*)d_in[9];
    const float* edge_enc_b = (const float*)d_in[10];
    const float* pre_W      = (const float*)d_in[11];
    const float* pre_b      = (const float*)d_in[12];
    const float* post_W     = (const float*)d_in[13];
    const float* post_b     = (const float*)d_in[14];
    const float* lin_W      = (const float*)d_in[15];
    const float* lin_b      = (const float*)d_in[16];
    const float* head_W     = (const float*)d_in[17];
    const float* head_b     = (const float*)d_in[18];
    float* out = (float*)d_out;

    char* wp = (char*)d_ws;
    auto carve = [&](size_t bytes) -> char* {
        char* r = wp;
        wp += (bytes + 255) & ~(size_t)255;
        return r;
    };
    int*   deg     = (int*)carve((size_t)NN * 4);      // |
    int*   cursor  = (int*)carve((size_t)NN * 4);      // | zeroed in ONE memset
    float* sumlog  = (float*)carve(4);                 // |
    int*   partial = (int*)carve(256 * 4);
    int*   row_ptr = (int*)carve((size_t)(NN + 1) * 4);
    int*   csr_src = (int*)carve((size_t)NE * 4);
    int*   csr_eid = (int*)carve((size_t)NE * 4);
    float* amp     = (float*)carve((size_t)NN * 4);
    float* att     = (float*)carve((size_t)NN * 4);
    float* Kc      = (float*)carve((size_t)NL * 16 * H * 4);
    float* cc      = (float*)carve((size_t)NL * H * 4);
    float* cfold   = (float*)carve((size_t)NL * H * 4);
    float* Mf      = (float*)carve((size_t)NL * H * H * 4);
    float* eattrF  = (float*)carve((size_t)NE * EIN * 4);
    unsigned short* embWt  = (unsigned short*)carve((size_t)H * FIN * 2);
    unsigned short* Wt3    = (unsigned short*)carve((size_t)NL * 3 * H * H * 2);
    unsigned short* foldT  = (unsigned short*)carve((size_t)NL * 128 * 1664 * 2);
    unsigned short* xb     = (unsigned short*)carve((size_t)NN * FIN * 2);
    unsigned short* hb     = (unsigned short*)carve((size_t)NN * H * 2);
    unsigned short* planesB= (unsigned short*)carve((size_t)3 * NN * H * 2);
    unsigned short* aggb   = (unsigned short*)carve((size_t)NN * 4 * H * 2);
    float* hf      = (float*)carve((size_t)NN * H * 4);

    const size_t NP = (size_t)NN * H;

    // deg, cursor, sumlog are contiguous carves (256-aligned): one memset
    hipMemsetAsync(deg, 0, ((size_t)NN * 4 + 255 & ~(size_t)255) * 2 + 256, stream);

    k_hist<<<(NE + 255) / 256, 256, 0, stream>>>(dst, deg);
    k_scan1<<<NBLK, 256, 0, stream>>>(deg, partial);
    k_scan2<<<1, 256, 0, stream>>>(partial, row_ptr, NBLK);
    k_scan3<<<NBLK, 256, 0, stream>>>(deg, partial, row_ptr);
    k_fill<<<(NE + 255) / 256, 256, 0, stream>>>(src, dst, row_ptr, cursor, csr_src, csr_eid);
    k_eperm<<<(NE * EIN + 255) / 256, 256, 0, stream>>>(edge_attr, csr_eid, eattrF);
    k_sumlog<<<NBLK, 256, 0, stream>>>(deg, sumlog);
    k_scalers<<<NBLK, 256, 0, stream>>>(deg, sumlog, amp, att);
    k_encfold<<<dim3(2, NL), 256, 0, stream>>>(edge_enc_W, pre_W, Mf);
    k_kprep<<<dim3(8, NL), 256, 0, stream>>>(edge_emb_W, Mf, Kc);
    k_cprep<<<NL, H, 0, stream>>>(edge_emb_b, edge_enc_W, edge_enc_b, pre_W, pre_b, cc);
    k_wfold<<<dim3(26, NL), 256, 0, stream>>>(post_W, lin_W, Wt3, foldT);
    k_bfold<<<NL, H, 0, stream>>>(post_b, lin_b, lin_W, cfold);

    TDs tds;
    int nd = 0;
    tds.t[nd++] = TD{node_emb_W, embWt, FIN};
    for (int l = 0; l < NL; l++) {
        tds.t[nd++] = TD{pre_W + (size_t)l * 3 * H * H,         Wt3 + (size_t)(l * 3 + 0) * H * H, H};
        tds.t[nd++] = TD{pre_W + (size_t)l * 3 * H * H + H * H, Wt3 + (size_t)(l * 3 + 1) * H * H, H};
    }
    k_prepw<<<dim3(64, 9), 256, 0, stream>>>(tds);
    k_cast<<<(NN * FIN + 255) / 256, 256, 0, stream>>>(x, xb, NN * FIN);

    // h = x @ node_emb_W + b  (bf16 out)
    k_mgemm<<<dim3(1, GB2), 256, 0, stream>>>(xb, FIN, FIN, 1, embWt, FIN, 0,
                                              node_emb_b, hb);

    for (int l = 0; l < NL; l++) {
        int last = (l == NL - 1);
        // planesB bf16: [hW_dst | hW_src | hA'(=h@Wh@linW)]
        k_mgemm<<<dim3(3, GB2), 256, 0, stream>>>(hb, H, H, 2,
                                                  Wt3 + (size_t)l * 3 * H * H, H, H * H,
                                                  nullptr, planesB);
        // fused aggregation
        k_agg2<<<NN / 4, 256, 0, stream>>>(planesB, planesB + NP,
                                           eattrF, csr_src, row_ptr,
                                           Kc + (size_t)l * 16 * H, cc + (size_t)l * H,
                                           aggb);
        // fused parts GEMM + combine -> h (bf16; +fp32 on last layer)
        k_pgemm<<<GB3, 256, 0, stream>>>(aggb, foldT + (size_t)l * 128 * 1664,
                                         planesB + 2 * NP, amp, att,
                                         cfold + (size_t)l * H,
                                         hb, last ? hf : nullptr);
    }

    k_pool<<<NG, 256, 0, stream>>>(hf, batch, head_W, head_b, out);
}